// Round 7
// baseline (300.389 us; speedup 1.0000x reference)
//
#include <hip/hip_runtime.h>

#define N_NODES 40000
#define N_EDGES 640000
#define IN_F 128
#define HID_F 256
#define CLS_F 40
#define CLS_P 48      // padded to 3 MFMA tiles of 16
#define MB 32         // nodes per block in fused MLP (2 row-tiles of 16; 1250 blocks)
#define TS_LD 264     // ushort row stride: MUST be >= 256 (row width); 528B, 16B-aligned
#define SLICES 8      // feature-dim slices, one per XCD (bid&7 -> XCD round-robin)
#define SLICE_F 16    // fp32 cols per slice = 64B = one cache line per edge

typedef __attribute__((ext_vector_type(8))) short bf16x8;
typedef __attribute__((ext_vector_type(4))) float f32x4;

#define MFMA(a, b, c) __builtin_amdgcn_mfma_f32_16x16x32_bf16(a, b, c, 0, 0, 0)

__device__ __forceinline__ unsigned short f32_to_bf16_rne(float f) {
    unsigned int u = __float_as_uint(f);
    unsigned int r = u + 0x7fffu + ((u >> 16) & 1u);
    return (unsigned short)(r >> 16);
}

// ---------------- CSR build ----------------

__global__ void k_count(const int* __restrict__ dst, int* __restrict__ counts) {
    int e = blockIdx.x * blockDim.x + threadIdx.x;
    if (e < N_EDGES) atomicAdd(&counts[dst[e]], 1);
}

__global__ void k_scan1(const int* __restrict__ counts, int* __restrict__ bsum) {
    __shared__ int s[256];
    int i = blockIdx.x * 256 + threadIdx.x;
    s[threadIdx.x] = (i < N_NODES) ? counts[i] : 0;
    __syncthreads();
    for (int off = 128; off > 0; off >>= 1) {
        if (threadIdx.x < off) s[threadIdx.x] += s[threadIdx.x + off];
        __syncthreads();
    }
    if (threadIdx.x == 0) bsum[blockIdx.x] = s[0];
}

// parallel exclusive scan over <=256 block sums (157 used)
__global__ void k_scan2(int* __restrict__ bsum, int nb) {
    __shared__ int s[256];
    int t = threadIdx.x;
    int v = (t < nb) ? bsum[t] : 0;
    s[t] = v;
    __syncthreads();
    for (int off = 1; off < 256; off <<= 1) {
        int x = (t >= off) ? s[t - off] : 0;
        __syncthreads();
        s[t] += x;
        __syncthreads();
    }
    if (t < nb) bsum[t] = s[t] - v;   // exclusive
}

__global__ void k_scan3(const int* __restrict__ counts, const int* __restrict__ bsum,
                        int* __restrict__ rowptr, int* __restrict__ cursor) {
    __shared__ int s[256];
    int t = threadIdx.x;
    int i = blockIdx.x * 256 + t;
    int v = (i < N_NODES) ? counts[i] : 0;
    s[t] = v;
    __syncthreads();
    for (int off = 1; off < 256; off <<= 1) {
        int x = (t >= off) ? s[t - off] : 0;
        __syncthreads();
        s[t] += x;
        __syncthreads();
    }
    if (i < N_NODES) {
        int excl = s[t] - v + bsum[blockIdx.x];
        rowptr[i] = excl;
        cursor[i] = excl;
    }
}

__global__ void k_norm(const int* __restrict__ counts,
                       float* __restrict__ norm, float* __restrict__ norm2) {
    int i = blockIdx.x * blockDim.x + threadIdx.x;
    if (i < N_NODES) {
        float d = (float)counts[i];
        float r = rsqrtf(fmaxf(d, 1.0f));
        norm[i] = r;
        norm2[i] = r * r;
    }
}

__global__ void k_fill(const int* __restrict__ src, const int* __restrict__ dst,
                       int* __restrict__ cursor, int* __restrict__ csr_src) {
    int e = blockIdx.x * blockDim.x + threadIdx.x;
    if (e < N_EDGES) {
        int d = dst[e];
        int p = atomicAdd(&cursor[d], 1);
        csr_src[p] = src[e];
    }
}

// ---------------- pre-scale: xs[n][:] = features[n][:] * norm[n] ----------------
// Hoists the per-edge scale[src] gather out of the hops entirely.

__global__ __launch_bounds__(256) void k_scale(
        const float* __restrict__ f, const float* __restrict__ norm,
        float* __restrict__ xs) {
    int i = blockIdx.x * 256 + threadIdx.x;        // float4 index, 1.28M total
    float4 v = ((const float4*)f)[i];
    float s = norm[i >> 5];                        // 32 float4 per row
    v.x *= s; v.y *= s; v.z *= s; v.w *= s;
    ((float4*)xs)[i] = v;
}

// ---------------- propagation hop: XCD-sharded slice gather ----------------
// slice = blockIdx&7 -> same slice always lands on the same XCD (round-robin
// dispatch), so each XCD's 4MB L2 holds only its 2.56MB column slice ->
// gather becomes L2-resident. 4-lane groups, 64 nodes/block, 64B (one cache
// line) per edge. Pure gather-sum; dst-side scaling folded into epilogue.

#define HOP_SLICED_GATHER                                                     \
    int slice = blockIdx.x & (SLICES - 1);                                    \
    int chunk = blockIdx.x >> 3;                                              \
    int t   = threadIdx.x;                                                    \
    int gid = chunk * 64 + (t >> 2);   /* 40000 = 625*64, no bounds check */  \
    int ln  = t & 3;                                                          \
    int start = rowptr[gid];                                                  \
    int cnt   = counts[gid];                                                  \
    const float* base = gin + slice * SLICE_F + ln * 4;                       \
    float4 acc = make_float4(0.f, 0.f, 0.f, 0.f);                             \
    int i = 0;                                                                \
    for (; i + 3 < cnt; i += 4) {                                             \
        int s0 = csr_src[start + i];     int s1 = csr_src[start + i + 1];     \
        int s2 = csr_src[start + i + 2]; int s3 = csr_src[start + i + 3];     \
        float4 v0 = *(const float4*)(base + (size_t)s0 * IN_F);               \
        float4 v1 = *(const float4*)(base + (size_t)s1 * IN_F);               \
        float4 v2 = *(const float4*)(base + (size_t)s2 * IN_F);               \
        float4 v3 = *(const float4*)(base + (size_t)s3 * IN_F);               \
        acc.x += v0.x + v1.x + v2.x + v3.x;                                   \
        acc.y += v0.y + v1.y + v2.y + v3.y;                                   \
        acc.z += v0.z + v1.z + v2.z + v3.z;                                   \
        acc.w += v0.w + v1.w + v2.w + v3.w;                                   \
    }                                                                         \
    for (; i < cnt; i++) {                                                    \
        int s = csr_src[start + i];                                           \
        float4 v = *(const float4*)(base + (size_t)s * IN_F);                 \
        acc.x += v.x; acc.y += v.y; acc.z += v.z; acc.w += v.w;               \
    }

// hop1: gout[n] = oscale[n] * sum_{s in in(n)} gin[s]   (oscale = norm^2)
__global__ __launch_bounds__(256) void k_hop(
        const float* __restrict__ gin, float* __restrict__ gout,
        const int* __restrict__ csr_src, const int* __restrict__ rowptr,
        const int* __restrict__ counts, const float* __restrict__ oscale) {
    HOP_SLICED_GATHER
    float sc = oscale[gid];
    acc.x *= sc; acc.y *= sc; acc.z *= sc; acc.w *= sc;
    *(float4*)(gout + (size_t)gid * IN_F + slice * SLICE_F + ln * 4) = acc;
}

// hop2: bf16 hi/lo split output, oscale = norm (trailing norm of SGConv)
__global__ __launch_bounds__(256) void k_hop_split(
        const float* __restrict__ gin,
        unsigned short* __restrict__ ghi, unsigned short* __restrict__ glo,
        const int* __restrict__ csr_src, const int* __restrict__ rowptr,
        const int* __restrict__ counts, const float* __restrict__ oscale) {
    HOP_SLICED_GATHER
    float sc = oscale[gid];
    float vv[4] = {acc.x * sc, acc.y * sc, acc.z * sc, acc.w * sc};
    ushort4 h, l;
    unsigned short* hp = (unsigned short*)&h;
    unsigned short* lp = (unsigned short*)&l;
    #pragma unroll
    for (int j = 0; j < 4; j++) {
        unsigned short hi = f32_to_bf16_rne(vv[j]);
        float fh = __uint_as_float((unsigned)hi << 16);
        hp[j] = hi;
        lp[j] = f32_to_bf16_rne(vv[j] - fh);
    }
    size_t off = (size_t)gid * IN_F + slice * SLICE_F + ln * 4;
    *(ushort4*)(ghi + off) = h;
    *(ushort4*)(glo + off) = l;
}

// ---------------- weight prep: split fp32 -> bf16 hi/lo, transposed [col][k] ----------------

__global__ __launch_bounds__(256) void k_prep(
        const float* __restrict__ W1, const float* __restrict__ W2,
        unsigned short* __restrict__ w1hi, unsigned short* __restrict__ w1lo,
        unsigned short* __restrict__ w2hi, unsigned short* __restrict__ w2lo) {
    int idx = blockIdx.x * 256 + threadIdx.x;
    if (idx < IN_F * HID_F) {
        int k = idx >> 8;
        int c = idx & 255;
        float v = W1[idx];
        unsigned short hi = f32_to_bf16_rne(v);
        float fh = __uint_as_float((unsigned)hi << 16);
        unsigned short lo = f32_to_bf16_rne(v - fh);
        w1hi[c * IN_F + k] = hi;
        w1lo[c * IN_F + k] = lo;
    }
    int idx2 = idx - IN_F * HID_F;
    if (idx2 >= 0 && idx2 < CLS_P * HID_F) {
        int c = idx2 >> 8;
        int k = idx2 & 255;
        float v = (c < CLS_F) ? W2[k * CLS_F + c] : 0.f;
        unsigned short hi = f32_to_bf16_rne(v);
        float fh = __uint_as_float((unsigned)hi << 16);
        unsigned short lo = f32_to_bf16_rne(v - fh);
        w2hi[c * HID_F + k] = hi;
        w2lo[c * HID_F + k] = lo;
    }
}

// ---------------- fused MLP via split-bf16 MFMA, weights-in-registers ----------------
// D = Ahi*Bhi + Ahi*Blo + Alo*Bhi (fp32 accum).
// Block: 4 waves, MB=32 rows (2 row-tiles of 16). Wave w owns GEMM1 cols
// [w*64, w*64+64): its 32 W1 fragments (128 VGPR) are preloaded ONCE, then the
// 2 row-tiles stream through with A double-buffered. GEMM2: waves 0-2 each own
// one 16-class col-tile with 16 W2 fragments (64 VGPR) preloaded.

#define LOAD_A(AH, AL, rt) do {                                              \
    const unsigned short* hp_ = h2hi + (size_t)(n0 + (rt) * 16 + lr) * IN_F + lg * 8; \
    const unsigned short* lp_ = h2lo + (size_t)(n0 + (rt) * 16 + lr) * IN_F + lg * 8; \
    _Pragma("unroll")                                                        \
    for (int kq = 0; kq < 4; kq++) {                                         \
        AH[kq] = *(const bf16x8*)(hp_ + kq * 32);                            \
        AL[kq] = *(const bf16x8*)(lp_ + kq * 32);                            \
    }                                                                        \
} while (0)

#define TILE(AH, AL, rt) do {                                                \
    _Pragma("unroll")                                                        \
    for (int ct = 0; ct < 4; ct++) {                                         \
        f32x4 acc = {0.f, 0.f, 0.f, 0.f};                                    \
        _Pragma("unroll")                                                    \
        for (int kq = 0; kq < 4; kq++) {                                     \
            acc = MFMA(AH[kq], b1h[ct][kq], acc);                            \
            acc = MFMA(AH[kq], b1l[ct][kq], acc);                            \
            acc = MFMA(AL[kq], b1h[ct][kq], acc);                            \
        }                                                                    \
        int col_ = w * 64 + ct * 16 + lr;                                    \
        _Pragma("unroll")                                                    \
        for (int r = 0; r < 4; r++) {                                        \
            int row_ = (rt) * 16 + lg * 4 + r;                               \
            float v_ = acc[r] + b1v[ct];                                     \
            v_ = v_ > 0.f ? v_ : 0.f;                                        \
            unsigned short hi_ = f32_to_bf16_rne(v_);                        \
            float fh_ = __uint_as_float((unsigned)hi_ << 16);                \
            tshi[row_ * TS_LD + col_] = hi_;                                 \
            tslo[row_ * TS_LD + col_] = f32_to_bf16_rne(v_ - fh_);           \
        }                                                                    \
    }                                                                        \
} while (0)

__global__ __launch_bounds__(256, 2) void k_mlp(
        const unsigned short* __restrict__ h2hi, const unsigned short* __restrict__ h2lo,
        const unsigned short* __restrict__ w1hi, const unsigned short* __restrict__ w1lo,
        const float* __restrict__ b1,
        const unsigned short* __restrict__ w2hi, const unsigned short* __restrict__ w2lo,
        const float* __restrict__ b2,
        float* __restrict__ out) {
    __shared__ __align__(16) unsigned short tshi[MB * TS_LD];  // 16.5 KB
    __shared__ __align__(16) unsigned short tslo[MB * TS_LD];  // 16.5 KB
    int n0 = blockIdx.x * MB;
    int t  = threadIdx.x;
    int w  = t >> 6;
    int l  = t & 63;
    int lr = l & 15;     // A-row / B-col within tile
    int lg = l >> 4;     // k-group

    // ---- preload W1 fragments for this wave's 64 cols: 32 frags = 128 VGPR ----
    bf16x8 b1h[4][4], b1l[4][4];
    float  b1v[4];
    #pragma unroll
    for (int ct = 0; ct < 4; ct++) {
        int col = w * 64 + ct * 16 + lr;
        const unsigned short* bhp = w1hi + (size_t)col * IN_F + lg * 8;
        const unsigned short* blp = w1lo + (size_t)col * IN_F + lg * 8;
        #pragma unroll
        for (int kq = 0; kq < 4; kq++) {
            b1h[ct][kq] = *(const bf16x8*)(bhp + kq * 32);
            b1l[ct][kq] = *(const bf16x8*)(blp + kq * 32);
        }
        b1v[ct] = b1[col];
    }

    // ---- GEMM1 over 2 row-tiles, A double-buffered ----
    bf16x8 aAh[4], aAl[4], aBh[4], aBl[4];
    LOAD_A(aAh, aAl, 0);
    LOAD_A(aBh, aBl, 1);
    TILE(aAh, aAl, 0);
    TILE(aBh, aBl, 1);
    __syncthreads();

    // ---- GEMM2: waves 0-2, one 16-class col-tile each, W2 frags in regs ----
    if (w < 3) {
        int col = w * 16 + lr;                     // 0..47 (padded)
        bf16x8 b2h[8], b2l[8];
        const unsigned short* bhp = w2hi + (size_t)col * HID_F + lg * 8;
        const unsigned short* blp = w2lo + (size_t)col * HID_F + lg * 8;
        #pragma unroll
        for (int kk = 0; kk < 8; kk++) {
            b2h[kk] = *(const bf16x8*)(bhp + kk * 32);
            b2l[kk] = *(const bf16x8*)(blp + kk * 32);
        }
        float bias = (col < CLS_F) ? b2[col] : 0.f;
        #pragma unroll
        for (int rt2 = 0; rt2 < 2; rt2++) {
            const unsigned short* ahp = tshi + (rt2 * 16 + lr) * TS_LD + lg * 8;
            const unsigned short* alp = tslo + (rt2 * 16 + lr) * TS_LD + lg * 8;
            f32x4 acc0 = {0.f, 0.f, 0.f, 0.f};
            f32x4 acc1 = {0.f, 0.f, 0.f, 0.f};
            #pragma unroll
            for (int kk = 0; kk < 4; kk++) {
                bf16x8 a_h0 = *(const bf16x8*)(ahp + kk * 32);
                bf16x8 a_l0 = *(const bf16x8*)(alp + kk * 32);
                bf16x8 a_h1 = *(const bf16x8*)(ahp + (kk + 4) * 32);
                bf16x8 a_l1 = *(const bf16x8*)(alp + (kk + 4) * 32);
                acc0 = MFMA(a_h0, b2h[kk], acc0);
                acc1 = MFMA(a_h1, b2h[kk + 4], acc1);
                acc0 = MFMA(a_h0, b2l[kk], acc0);
                acc1 = MFMA(a_h1, b2l[kk + 4], acc1);
                acc0 = MFMA(a_l0, b2h[kk], acc0);
                acc1 = MFMA(a_l1, b2h[kk + 4], acc1);
            }
            if (col < CLS_F) {
                #pragma unroll
                for (int r = 0; r < 4; r++) {
                    int mrow = n0 + rt2 * 16 + lg * 4 + r;
                    out[(size_t)mrow * CLS_F + col] = acc0[r] + acc1[r] + bias;
                }
            }
        }
    }
}

// ---------------- launch ----------------

extern "C" void kernel_launch(void* const* d_in, const int* in_sizes, int n_in,
                              void* d_out, int out_size, void* d_ws, size_t ws_size,
                              hipStream_t stream) {
    const float* features = (const float*)d_in[0];
    const int*   src      = (const int*)d_in[1];
    const int*   dst      = (const int*)d_in[2];
    const float* W1       = (const float*)d_in[3];
    const float* b1       = (const float*)d_in[4];
    const float* W2       = (const float*)d_in[5];
    const float* b2       = (const float*)d_in[6];
    float*       out      = (float*)d_out;

    char* ws = (char*)d_ws;
    size_t off = 0;
    auto alloc = [&](size_t bytes) -> void* {
        void* p = ws + off;
        off += (bytes + 255) & ~(size_t)255;
        return p;
    };
    int*   counts = (int*)alloc((size_t)N_NODES * 4);
    int*   rowptr = (int*)alloc((size_t)N_NODES * 4);
    int*   cursor = (int*)alloc((size_t)N_NODES * 4);
    int*   bsum   = (int*)alloc(256 * 4);
    float* norm   = (float*)alloc((size_t)N_NODES * 4);
    float* norm2  = (float*)alloc((size_t)N_NODES * 4);
    int*   csr    = (int*)alloc((size_t)N_EDGES * 4);
    float* xs     = (float*)alloc((size_t)N_NODES * IN_F * 4);
    float* h1     = (float*)alloc((size_t)N_NODES * IN_F * 4);
    unsigned short* h2hi = (unsigned short*)alloc((size_t)N_NODES * IN_F * 2);
    unsigned short* h2lo = (unsigned short*)alloc((size_t)N_NODES * IN_F * 2);
    unsigned short* w1hi = (unsigned short*)alloc((size_t)HID_F * IN_F * 2);
    unsigned short* w1lo = (unsigned short*)alloc((size_t)HID_F * IN_F * 2);
    unsigned short* w2hi = (unsigned short*)alloc((size_t)CLS_P * HID_F * 2);
    unsigned short* w2lo = (unsigned short*)alloc((size_t)CLS_P * HID_F * 2);

    hipMemsetAsync(counts, 0, (size_t)N_NODES * 4, stream);

    int nb = (N_NODES + 255) / 256;   // 157
    k_count<<<(N_EDGES + 255) / 256, 256, 0, stream>>>(dst, counts);
    k_prep<<<(IN_F * HID_F + CLS_P * HID_F + 255) / 256, 256, 0, stream>>>(
        W1, W2, w1hi, w1lo, w2hi, w2lo);
    k_scan1<<<nb, 256, 0, stream>>>(counts, bsum);
    k_scan2<<<1, 256, 0, stream>>>(bsum, nb);
    k_scan3<<<nb, 256, 0, stream>>>(counts, bsum, rowptr, cursor);
    k_norm<<<nb, 256, 0, stream>>>(counts, norm, norm2);
    k_fill<<<(N_EDGES + 255) / 256, 256, 0, stream>>>(src, dst, cursor, csr);

    // pre-scale by norm[src]; hops are pure gathers with dst-side epilogue scaling
    k_scale<<<N_NODES * (IN_F / 4) / 256, 256, 0, stream>>>(features, norm, xs);
    k_hop<<<SLICES * (N_NODES / 64), 256, 0, stream>>>(xs, h1, csr, rowptr, counts, norm2);
    k_hop_split<<<SLICES * (N_NODES / 64), 256, 0, stream>>>(h1, h2hi, h2lo, csr, rowptr,
                                                             counts, norm);

    k_mlp<<<N_NODES / MB, 256, 0, stream>>>(h2hi, h2lo, w1hi, w1lo, b1, w2hi, w2lo, b2, out);
}

// Round 8
// 237.572 us; speedup vs baseline: 1.2644x; 1.2644x over previous
//
#include <hip/hip_runtime.h>

#define N_NODES 40000
#define N_EDGES 640000
#define IN_F 128
#define HID_F 256
#define CLS_F 40
#define CLS_P 48      // padded to 3 MFMA tiles of 16
#define MB 32         // nodes per block in fused MLP (2 row-tiles of 16; 1250 blocks)
#define TS_LD 264     // ushort row stride: MUST be >= 256 (row width); 528B, 16B-aligned

typedef __attribute__((ext_vector_type(8))) short bf16x8;
typedef __attribute__((ext_vector_type(4))) float f32x4;
typedef __attribute__((ext_vector_type(4))) _Float16 half4;
typedef __attribute__((ext_vector_type(8))) _Float16 half8;

#define MFMA(a, b, c) __builtin_amdgcn_mfma_f32_16x16x32_bf16(a, b, c, 0, 0, 0)

__device__ __forceinline__ unsigned short f32_to_bf16_rne(float f) {
    unsigned int u = __float_as_uint(f);
    unsigned int r = u + 0x7fffu + ((u >> 16) & 1u);
    return (unsigned short)(r >> 16);
}

// ---------------- CSR build ----------------

__global__ void k_count(const int* __restrict__ dst, int* __restrict__ counts) {
    int e = blockIdx.x * blockDim.x + threadIdx.x;
    if (e < N_EDGES) atomicAdd(&counts[dst[e]], 1);
}

__global__ void k_scan1(const int* __restrict__ counts, int* __restrict__ bsum) {
    __shared__ int s[256];
    int i = blockIdx.x * 256 + threadIdx.x;
    s[threadIdx.x] = (i < N_NODES) ? counts[i] : 0;
    __syncthreads();
    for (int off = 128; off > 0; off >>= 1) {
        if (threadIdx.x < off) s[threadIdx.x] += s[threadIdx.x + off];
        __syncthreads();
    }
    if (threadIdx.x == 0) bsum[blockIdx.x] = s[0];
}

// parallel exclusive scan over <=256 block sums (157 used)
__global__ void k_scan2(int* __restrict__ bsum, int nb) {
    __shared__ int s[256];
    int t = threadIdx.x;
    int v = (t < nb) ? bsum[t] : 0;
    s[t] = v;
    __syncthreads();
    for (int off = 1; off < 256; off <<= 1) {
        int x = (t >= off) ? s[t - off] : 0;
        __syncthreads();
        s[t] += x;
        __syncthreads();
    }
    if (t < nb) bsum[t] = s[t] - v;   // exclusive
}

__global__ void k_scan3(const int* __restrict__ counts, const int* __restrict__ bsum,
                        int* __restrict__ rowptr, int* __restrict__ cursor) {
    __shared__ int s[256];
    int t = threadIdx.x;
    int i = blockIdx.x * 256 + t;
    int v = (i < N_NODES) ? counts[i] : 0;
    s[t] = v;
    __syncthreads();
    for (int off = 1; off < 256; off <<= 1) {
        int x = (t >= off) ? s[t - off] : 0;
        __syncthreads();
        s[t] += x;
        __syncthreads();
    }
    if (i < N_NODES) {
        int excl = s[t] - v + bsum[blockIdx.x];
        rowptr[i] = excl;
        cursor[i] = excl;
    }
}

__global__ void k_norm(const int* __restrict__ counts,
                       float* __restrict__ norm, float* __restrict__ norm2) {
    int i = blockIdx.x * blockDim.x + threadIdx.x;
    if (i < N_NODES) {
        float d = (float)counts[i];
        float r = rsqrtf(fmaxf(d, 1.0f));
        norm[i] = r;
        norm2[i] = r * r;
    }
}

__global__ void k_fill(const int* __restrict__ src, const int* __restrict__ dst,
                       int* __restrict__ cursor, unsigned short* __restrict__ csr_src) {
    int e = blockIdx.x * blockDim.x + threadIdx.x;
    if (e < N_EDGES) {
        int d = dst[e];
        int p = atomicAdd(&cursor[d], 1);
        csr_src[p] = (unsigned short)src[e];   // N_NODES=40000 < 65536
    }
}

// ---------------- pre-scale + fp16 convert: xs[n][:] = fp16(features[n][:] * norm[n]) ----
// Hoists the per-edge scale[src] gather out of the hops AND halves the gather
// table width (512B -> 256B rows).

__global__ __launch_bounds__(256) void k_scale(
        const float* __restrict__ f, const float* __restrict__ norm,
        _Float16* __restrict__ xs) {
    int i = blockIdx.x * 256 + threadIdx.x;        // 8 floats per thread, 640000 total
    float s = norm[i >> 4];                        // 16 threads per 128-elem row
    float4 a = ((const float4*)f)[i * 2];
    float4 b = ((const float4*)f)[i * 2 + 1];
    half8 h;
    h[0] = (_Float16)(a.x * s); h[1] = (_Float16)(a.y * s);
    h[2] = (_Float16)(a.z * s); h[3] = (_Float16)(a.w * s);
    h[4] = (_Float16)(b.x * s); h[5] = (_Float16)(b.y * s);
    h[6] = (_Float16)(b.z * s); h[7] = (_Float16)(b.w * s);
    ((half8*)xs)[i] = h;
}

// ---------------- propagation hop (gather, no atomics), fp16 tables ----------------
// 32 lanes per node, half4 (8B) per lane -> one 256B row read per edge.
// Pure gather-sum in fp32; dst-side scaling in epilogue.
// h2[n] = norm_n * sum_s h1[s],  h1[s] = norm2_s * sum_t xs[t],  xs = fp16(x*norm).

#define HOP_GATHER16                                                          \
    int gid  = blockIdx.x * 8 + (threadIdx.x >> 5);                           \
    int lane = threadIdx.x & 31;                                              \
    if (gid >= N_NODES) return;                                               \
    int start = rowptr[gid];                                                  \
    int cnt   = counts[gid];                                                  \
    const _Float16* base = gin + lane * 4;                                    \
    float4 acc = make_float4(0.f, 0.f, 0.f, 0.f);                             \
    int i = 0;                                                                \
    for (; i + 3 < cnt; i += 4) {                                             \
        int s0 = csr_src[start + i];     int s1 = csr_src[start + i + 1];     \
        int s2 = csr_src[start + i + 2]; int s3 = csr_src[start + i + 3];     \
        half4 v0 = *(const half4*)(base + (size_t)s0 * IN_F);                 \
        half4 v1 = *(const half4*)(base + (size_t)s1 * IN_F);                 \
        half4 v2 = *(const half4*)(base + (size_t)s2 * IN_F);                 \
        half4 v3 = *(const half4*)(base + (size_t)s3 * IN_F);                 \
        acc.x += (float)v0[0] + (float)v1[0] + (float)v2[0] + (float)v3[0];   \
        acc.y += (float)v0[1] + (float)v1[1] + (float)v2[1] + (float)v3[1];   \
        acc.z += (float)v0[2] + (float)v1[2] + (float)v2[2] + (float)v3[2];   \
        acc.w += (float)v0[3] + (float)v1[3] + (float)v2[3] + (float)v3[3];   \
    }                                                                         \
    for (; i < cnt; i++) {                                                    \
        int s = csr_src[start + i];                                           \
        half4 v = *(const half4*)(base + (size_t)s * IN_F);                   \
        acc.x += (float)v[0]; acc.y += (float)v[1];                           \
        acc.z += (float)v[2]; acc.w += (float)v[3];                           \
    }

// hop1: gout[n] = fp16( oscale[n] * sum )   (oscale = norm^2)
__global__ __launch_bounds__(256) void k_hop(
        const _Float16* __restrict__ gin, _Float16* __restrict__ gout,
        const unsigned short* __restrict__ csr_src, const int* __restrict__ rowptr,
        const int* __restrict__ counts, const float* __restrict__ oscale) {
    HOP_GATHER16
    float sc = oscale[gid];
    half4 o;
    o[0] = (_Float16)(acc.x * sc); o[1] = (_Float16)(acc.y * sc);
    o[2] = (_Float16)(acc.z * sc); o[3] = (_Float16)(acc.w * sc);
    *(half4*)(gout + (size_t)gid * IN_F + lane * 4) = o;
}

// hop2: bf16 hi/lo split output (feeds MFMA MLP), oscale = norm (trailing norm)
__global__ __launch_bounds__(256) void k_hop_split(
        const _Float16* __restrict__ gin,
        unsigned short* __restrict__ ghi, unsigned short* __restrict__ glo,
        const unsigned short* __restrict__ csr_src, const int* __restrict__ rowptr,
        const int* __restrict__ counts, const float* __restrict__ oscale) {
    HOP_GATHER16
    float sc = oscale[gid];
    float vv[4] = {acc.x * sc, acc.y * sc, acc.z * sc, acc.w * sc};
    ushort4 h, l;
    unsigned short* hp = (unsigned short*)&h;
    unsigned short* lp = (unsigned short*)&l;
    #pragma unroll
    for (int j = 0; j < 4; j++) {
        unsigned short hi = f32_to_bf16_rne(vv[j]);
        float fh = __uint_as_float((unsigned)hi << 16);
        hp[j] = hi;
        lp[j] = f32_to_bf16_rne(vv[j] - fh);
    }
    ((ushort4*)(ghi + (size_t)gid * IN_F))[lane] = h;
    ((ushort4*)(glo + (size_t)gid * IN_F))[lane] = l;
}

// ---------------- weight prep: split fp32 -> bf16 hi/lo, transposed [col][k] ----------------

__global__ __launch_bounds__(256) void k_prep(
        const float* __restrict__ W1, const float* __restrict__ W2,
        unsigned short* __restrict__ w1hi, unsigned short* __restrict__ w1lo,
        unsigned short* __restrict__ w2hi, unsigned short* __restrict__ w2lo) {
    int idx = blockIdx.x * 256 + threadIdx.x;
    if (idx < IN_F * HID_F) {
        int k = idx >> 8;
        int c = idx & 255;
        float v = W1[idx];
        unsigned short hi = f32_to_bf16_rne(v);
        float fh = __uint_as_float((unsigned)hi << 16);
        unsigned short lo = f32_to_bf16_rne(v - fh);
        w1hi[c * IN_F + k] = hi;
        w1lo[c * IN_F + k] = lo;
    }
    int idx2 = idx - IN_F * HID_F;
    if (idx2 >= 0 && idx2 < CLS_P * HID_F) {
        int c = idx2 >> 8;
        int k = idx2 & 255;
        float v = (c < CLS_F) ? W2[k * CLS_F + c] : 0.f;
        unsigned short hi = f32_to_bf16_rne(v);
        float fh = __uint_as_float((unsigned)hi << 16);
        unsigned short lo = f32_to_bf16_rne(v - fh);
        w2hi[c * HID_F + k] = hi;
        w2lo[c * HID_F + k] = lo;
    }
}

// ---------------- fused MLP via split-bf16 MFMA, weights-in-registers ----------------
// D = Ahi*Bhi + Ahi*Blo + Alo*Bhi (fp32 accum).
// Block: 4 waves, MB=32 rows (2 row-tiles of 16). Wave w owns GEMM1 cols
// [w*64, w*64+64): its 32 W1 fragments (128 VGPR) are preloaded ONCE, then the
// 2 row-tiles stream through with A double-buffered. GEMM2: waves 0-2 each own
// one 16-class col-tile with 16 W2 fragments (64 VGPR) preloaded.

#define LOAD_A(AH, AL, rt) do {                                              \
    const unsigned short* hp_ = h2hi + (size_t)(n0 + (rt) * 16 + lr) * IN_F + lg * 8; \
    const unsigned short* lp_ = h2lo + (size_t)(n0 + (rt) * 16 + lr) * IN_F + lg * 8; \
    _Pragma("unroll")                                                        \
    for (int kq = 0; kq < 4; kq++) {                                         \
        AH[kq] = *(const bf16x8*)(hp_ + kq * 32);                            \
        AL[kq] = *(const bf16x8*)(lp_ + kq * 32);                            \
    }                                                                        \
} while (0)

#define TILE(AH, AL, rt) do {                                                \
    _Pragma("unroll")                                                        \
    for (int ct = 0; ct < 4; ct++) {                                         \
        f32x4 acc = {0.f, 0.f, 0.f, 0.f};                                    \
        _Pragma("unroll")                                                    \
        for (int kq = 0; kq < 4; kq++) {                                     \
            acc = MFMA(AH[kq], b1h[ct][kq], acc);                            \
            acc = MFMA(AH[kq], b1l[ct][kq], acc);                            \
            acc = MFMA(AL[kq], b1h[ct][kq], acc);                            \
        }                                                                    \
        int col_ = w * 64 + ct * 16 + lr;                                    \
        _Pragma("unroll")                                                    \
        for (int r = 0; r < 4; r++) {                                        \
            int row_ = (rt) * 16 + lg * 4 + r;                               \
            float v_ = acc[r] + b1v[ct];                                     \
            v_ = v_ > 0.f ? v_ : 0.f;                                        \
            unsigned short hi_ = f32_to_bf16_rne(v_);                        \
            float fh_ = __uint_as_float((unsigned)hi_ << 16);                \
            tshi[row_ * TS_LD + col_] = hi_;                                 \
            tslo[row_ * TS_LD + col_] = f32_to_bf16_rne(v_ - fh_);           \
        }                                                                    \
    }                                                                        \
} while (0)

__global__ __launch_bounds__(256, 2) void k_mlp(
        const unsigned short* __restrict__ h2hi, const unsigned short* __restrict__ h2lo,
        const unsigned short* __restrict__ w1hi, const unsigned short* __restrict__ w1lo,
        const float* __restrict__ b1,
        const unsigned short* __restrict__ w2hi, const unsigned short* __restrict__ w2lo,
        const float* __restrict__ b2,
        float* __restrict__ out) {
    __shared__ __align__(16) unsigned short tshi[MB * TS_LD];  // 16.5 KB
    __shared__ __align__(16) unsigned short tslo[MB * TS_LD];  // 16.5 KB
    int n0 = blockIdx.x * MB;
    int t  = threadIdx.x;
    int w  = t >> 6;
    int l  = t & 63;
    int lr = l & 15;     // A-row / B-col within tile
    int lg = l >> 4;     // k-group

    // ---- preload W1 fragments for this wave's 64 cols: 32 frags = 128 VGPR ----
    bf16x8 b1h[4][4], b1l[4][4];
    float  b1v[4];
    #pragma unroll
    for (int ct = 0; ct < 4; ct++) {
        int col = w * 64 + ct * 16 + lr;
        const unsigned short* bhp = w1hi + (size_t)col * IN_F + lg * 8;
        const unsigned short* blp = w1lo + (size_t)col * IN_F + lg * 8;
        #pragma unroll
        for (int kq = 0; kq < 4; kq++) {
            b1h[ct][kq] = *(const bf16x8*)(bhp + kq * 32);
            b1l[ct][kq] = *(const bf16x8*)(blp + kq * 32);
        }
        b1v[ct] = b1[col];
    }

    // ---- GEMM1 over 2 row-tiles, A double-buffered ----
    bf16x8 aAh[4], aAl[4], aBh[4], aBl[4];
    LOAD_A(aAh, aAl, 0);
    LOAD_A(aBh, aBl, 1);
    TILE(aAh, aAl, 0);
    TILE(aBh, aBl, 1);
    __syncthreads();

    // ---- GEMM2: waves 0-2, one 16-class col-tile each, W2 frags in regs ----
    if (w < 3) {
        int col = w * 16 + lr;                     // 0..47 (padded)
        bf16x8 b2h[8], b2l[8];
        const unsigned short* bhp = w2hi + (size_t)col * HID_F + lg * 8;
        const unsigned short* blp = w2lo + (size_t)col * HID_F + lg * 8;
        #pragma unroll
        for (int kk = 0; kk < 8; kk++) {
            b2h[kk] = *(const bf16x8*)(bhp + kk * 32);
            b2l[kk] = *(const bf16x8*)(blp + kk * 32);
        }
        float bias = (col < CLS_F) ? b2[col] : 0.f;
        #pragma unroll
        for (int rt2 = 0; rt2 < 2; rt2++) {
            const unsigned short* ahp = tshi + (rt2 * 16 + lr) * TS_LD + lg * 8;
            const unsigned short* alp = tslo + (rt2 * 16 + lr) * TS_LD + lg * 8;
            f32x4 acc0 = {0.f, 0.f, 0.f, 0.f};
            f32x4 acc1 = {0.f, 0.f, 0.f, 0.f};
            #pragma unroll
            for (int kk = 0; kk < 4; kk++) {
                bf16x8 a_h0 = *(const bf16x8*)(ahp + kk * 32);
                bf16x8 a_l0 = *(const bf16x8*)(alp + kk * 32);
                bf16x8 a_h1 = *(const bf16x8*)(ahp + (kk + 4) * 32);
                bf16x8 a_l1 = *(const bf16x8*)(alp + (kk + 4) * 32);
                acc0 = MFMA(a_h0, b2h[kk], acc0);
                acc1 = MFMA(a_h1, b2h[kk + 4], acc1);
                acc0 = MFMA(a_h0, b2l[kk], acc0);
                acc1 = MFMA(a_h1, b2l[kk + 4], acc1);
                acc0 = MFMA(a_l0, b2h[kk], acc0);
                acc1 = MFMA(a_l1, b2h[kk + 4], acc1);
            }
            if (col < CLS_F) {
                #pragma unroll
                for (int r = 0; r < 4; r++) {
                    int mrow = n0 + rt2 * 16 + lg * 4 + r;
                    out[(size_t)mrow * CLS_F + col] = acc0[r] + acc1[r] + bias;
                }
            }
        }
    }
}

// ---------------- launch ----------------

extern "C" void kernel_launch(void* const* d_in, const int* in_sizes, int n_in,
                              void* d_out, int out_size, void* d_ws, size_t ws_size,
                              hipStream_t stream) {
    const float* features = (const float*)d_in[0];
    const int*   src      = (const int*)d_in[1];
    const int*   dst      = (const int*)d_in[2];
    const float* W1       = (const float*)d_in[3];
    const float* b1       = (const float*)d_in[4];
    const float* W2       = (const float*)d_in[5];
    const float* b2       = (const float*)d_in[6];
    float*       out      = (float*)d_out;

    char* ws = (char*)d_ws;
    size_t off = 0;
    auto alloc = [&](size_t bytes) -> void* {
        void* p = ws + off;
        off += (bytes + 255) & ~(size_t)255;
        return p;
    };
    int*   counts = (int*)alloc((size_t)N_NODES * 4);
    int*   rowptr = (int*)alloc((size_t)N_NODES * 4);
    int*   cursor = (int*)alloc((size_t)N_NODES * 4);
    int*   bsum   = (int*)alloc(256 * 4);
    float* norm   = (float*)alloc((size_t)N_NODES * 4);
    float* norm2  = (float*)alloc((size_t)N_NODES * 4);
    unsigned short* csr = (unsigned short*)alloc((size_t)N_EDGES * 2);
    _Float16* xs  = (_Float16*)alloc((size_t)N_NODES * IN_F * 2);
    _Float16* h1  = (_Float16*)alloc((size_t)N_NODES * IN_F * 2);
    unsigned short* h2hi = (unsigned short*)alloc((size_t)N_NODES * IN_F * 2);
    unsigned short* h2lo = (unsigned short*)alloc((size_t)N_NODES * IN_F * 2);
    unsigned short* w1hi = (unsigned short*)alloc((size_t)HID_F * IN_F * 2);
    unsigned short* w1lo = (unsigned short*)alloc((size_t)HID_F * IN_F * 2);
    unsigned short* w2hi = (unsigned short*)alloc((size_t)CLS_P * HID_F * 2);
    unsigned short* w2lo = (unsigned short*)alloc((size_t)CLS_P * HID_F * 2);

    hipMemsetAsync(counts, 0, (size_t)N_NODES * 4, stream);

    int nb = (N_NODES + 255) / 256;   // 157
    k_count<<<(N_EDGES + 255) / 256, 256, 0, stream>>>(dst, counts);
    k_prep<<<(IN_F * HID_F + CLS_P * HID_F + 255) / 256, 256, 0, stream>>>(
        W1, W2, w1hi, w1lo, w2hi, w2lo);
    k_scan1<<<nb, 256, 0, stream>>>(counts, bsum);
    k_scan2<<<1, 256, 0, stream>>>(bsum, nb);
    k_scan3<<<nb, 256, 0, stream>>>(counts, bsum, rowptr, cursor);
    k_norm<<<nb, 256, 0, stream>>>(counts, norm, norm2);
    k_fill<<<(N_EDGES + 255) / 256, 256, 0, stream>>>(src, dst, cursor, csr);

    // xs = fp16(features * norm[src-side]); hops are pure gathers, dst-side scaling
    k_scale<<<N_NODES * IN_F / 8 / 256, 256, 0, stream>>>(features, norm, xs);
    k_hop<<<(N_NODES + 7) / 8, 256, 0, stream>>>(xs, h1, csr, rowptr, counts, norm2);
    k_hop_split<<<(N_NODES + 7) / 8, 256, 0, stream>>>(h1, h2hi, h2lo, csr, rowptr,
                                                       counts, norm);

    k_mlp<<<N_NODES / MB, 256, 0, stream>>>(h2hi, h2lo, w1hi, w1lo, b1, w2hi, w2lo, b2, out);
}